// Round 6
// baseline (123.941 us; speedup 1.0000x reference)
//
#include <hip/hip_runtime.h>

// MultiThresholdLIFSpike: x [T=16, B=32, C=128, H=32, W=32] f32, raw thresholds [4] f32.
// Per spatial element, scan over T:
//   u = 0.25*mem*(1-spike) + x_t
//   s = sum_k sigmoid(10*(u - thr_k)),  thr_k = sigmoid(raw_k)
//   mem = u; spike = s; out[t] = s
//
// R6: explicit depth-3 software pipeline, tight reg budget.
//  - rotate 3 load buffers; issue load t+3 at TOP of iteration t, pinned by
//    sched_barrier(0) so it can't sink below the compute. Each wave keeps
//    2-3 loads in flight (24 KB/SIMD outstanding >> Little's-law ~5 KB).
//  - __launch_bounds__(256, 8): ~45 VGPR est., 8 waves/SIMD.
//  - shared-exp sigmoid: sigmoid(B*(u-thr_k)) = 1/(1 + e^{-B*u}*2^(S*thr_k)).

#define T_STEPS 16
#define NTHR 4

typedef float v4f __attribute__((ext_vector_type(4)));

__global__ __launch_bounds__(256, 8) void lif_spike_kernel(
    const float* __restrict__ x,
    const float* __restrict__ raw_thr,
    float* __restrict__ out,
    int n4 /* float4 groups per timestep */) {

    int i = blockIdx.x * blockDim.x + threadIdx.x;
    if (i >= n4) return;

    constexpr float LOG2E = 1.44269504088896340736f;
    constexpr float BETA  = 10.0f;
    constexpr float TAU   = 0.25f;
    constexpr float S     = BETA * LOG2E;

    float ck[NTHR];
#pragma unroll
    for (int k = 0; k < NTHR; ++k) {
        float thr = __builtin_amdgcn_rcpf(1.0f + __builtin_amdgcn_exp2f(-LOG2E * raw_thr[k]));
        ck[k] = __builtin_amdgcn_exp2f(S * thr);
    }

    const v4f* xv = reinterpret_cast<const v4f*>(x) + i;
    v4f*       ov = reinterpret_cast<v4f*>(out) + i;
    const size_t stride = (size_t)n4;

    // prologue: 3 loads in flight
    v4f buf[3];
    buf[0] = xv[0];
    buf[1] = xv[stride];
    buf[2] = xv[2 * stride];

    float mem[4] = {0.f, 0.f, 0.f, 0.f};
    float spk[4] = {0.f, 0.f, 0.f, 0.f};

#pragma unroll
    for (int t = 0; t < T_STEPS; ++t) {
        v4f cur = buf[t % 3];
        // issue the t+3 load BEFORE the dependent compute; pin it there
        if (t + 3 < T_STEPS)
            buf[t % 3] = xv[(size_t)(t + 3) * stride];
        __builtin_amdgcn_sched_barrier(0);

        float s[4];
#pragma unroll
        for (int j = 0; j < 4; ++j) {
            float tm = TAU * mem[j];
            float u  = __builtin_fmaf(-tm, spk[j], tm) + cur[j];  // tm*(1-spk)+x
            float E  = __builtin_amdgcn_exp2f(-S * u);            // e^{-B*u}
            float acc = 0.f;
#pragma unroll
            for (int k = 0; k < NTHR; ++k)
                acc += __builtin_amdgcn_rcpf(__builtin_fmaf(E, ck[k], 1.0f));
            mem[j] = u; spk[j] = acc; s[j] = acc;
        }
        v4f o = {s[0], s[1], s[2], s[3]};
        ov[(size_t)t * stride] = o;
    }
}

extern "C" void kernel_launch(void* const* d_in, const int* in_sizes, int n_in,
                              void* d_out, int out_size, void* d_ws, size_t ws_size,
                              hipStream_t stream) {
    const float* x       = (const float*)d_in[0];
    const float* raw_thr = (const float*)d_in[1];
    float*       out     = (float*)d_out;

    int n_spatial = in_sizes[0] / T_STEPS;   // 4,194,304
    int n4        = n_spatial / 4;           // 1,048,576

    const int block = 256;
    const int grid  = (n4 + block - 1) / block;  // 4096 blocks

    lif_spike_kernel<<<grid, block, 0, stream>>>(x, raw_thr, out, n4);
}

// Round 7
// 89.227 us; speedup vs baseline: 1.3890x; 1.3890x over previous
//
#include <hip/hip_runtime.h>

// MultiThresholdLIFSpike: x [T=16, B=32, C=128, H=32, W=32] f32, raw thresholds [4] f32.
// Per spatial element, scan over T:
//   u = 0.25*mem*(1-spike) + x_t
//   s = sum_k sigmoid(10*(u - thr_k)),  thr_k = sigmoid(raw_k)
//   mem = u; spike = s; out[t] = s
//
// R7: R4 structure (best known, VGPR=24, max occupancy) + ISOLATED change:
// nontemporal LOADS only. Read stream is touch-once; nt -> no L3 allocation,
// so the ~256MB of dirty output lines (L3 is 256MB, write-back) aren't
// force-evicted mid-kernel by read churn; writebacks defer/overlap.
// Stores stay cached (write-back). Everything else identical to R4.

#define T_STEPS 16
#define NTHR 4

typedef float v4f __attribute__((ext_vector_type(4)));

__global__ __launch_bounds__(256) void lif_spike_kernel(
    const float* __restrict__ x,
    const float* __restrict__ raw_thr,
    float* __restrict__ out,
    int n4 /* float4 groups per timestep */) {

    int i = blockIdx.x * blockDim.x + threadIdx.x;
    if (i >= n4) return;

    constexpr float LOG2E = 1.44269504088896340736f;
    constexpr float BETA  = 10.0f;
    constexpr float TAU   = 0.25f;
    constexpr float S     = BETA * LOG2E;

    // c_k = 2^(S * sigmoid(raw_k)); 4 broadcast loads, cached
    float ck[NTHR];
#pragma unroll
    for (int k = 0; k < NTHR; ++k) {
        float thr = __builtin_amdgcn_rcpf(1.0f + __builtin_amdgcn_exp2f(-LOG2E * raw_thr[k]));
        ck[k] = __builtin_amdgcn_exp2f(S * thr);
    }

    const v4f* xv = reinterpret_cast<const v4f*>(x) + i;
    v4f*       ov = reinterpret_cast<v4f*>(out) + i;

    float mem[4] = {0.f, 0.f, 0.f, 0.f};
    float spk[4] = {0.f, 0.f, 0.f, 0.f};

#pragma unroll
    for (int t = 0; t < T_STEPS; ++t) {
        v4f xt = __builtin_nontemporal_load(xv + (size_t)t * (size_t)n4);

        float s[4];
#pragma unroll
        for (int j = 0; j < 4; ++j) {
            float tm = TAU * mem[j];
            float u  = __builtin_fmaf(-tm, spk[j], tm) + xt[j];  // tm*(1-spk)+x
            float E  = __builtin_amdgcn_exp2f(-S * u);           // e^{-B*u}
            float acc = 0.f;
#pragma unroll
            for (int k = 0; k < NTHR; ++k)
                acc += __builtin_amdgcn_rcpf(__builtin_fmaf(E, ck[k], 1.0f));
            mem[j] = u; spk[j] = acc; s[j] = acc;
        }
        v4f o = {s[0], s[1], s[2], s[3]};
        ov[(size_t)t * (size_t)n4] = o;   // cached write-back store
    }
}

extern "C" void kernel_launch(void* const* d_in, const int* in_sizes, int n_in,
                              void* d_out, int out_size, void* d_ws, size_t ws_size,
                              hipStream_t stream) {
    const float* x       = (const float*)d_in[0];
    const float* raw_thr = (const float*)d_in[1];
    float*       out     = (float*)d_out;

    int n_spatial = in_sizes[0] / T_STEPS;   // 4,194,304
    int n4        = n_spatial / 4;           // 1,048,576

    const int block = 256;
    const int grid  = (n4 + block - 1) / block;  // 4096 blocks

    lif_spike_kernel<<<grid, block, 0, stream>>>(x, raw_thr, out, n4);
}